// Round 3
// baseline (465.772 us; speedup 1.0000x reference)
//
#include <hip/hip_runtime.h>

#define NN 8192
#define DD 128
#define CH 8            // column chunks
#define CPC (NN / CH)   // cols per chunk = 1024
#define TILES (CPC / 64)

typedef __bf16 bf16x8 __attribute__((ext_vector_type(8)));
typedef float f32x4 __attribute__((ext_vector_type(4)));

__device__ inline unsigned short f2bf(float f) {
  unsigned u = __float_as_uint(f);
  u += 0x7FFFu + ((u >> 16) & 1u);   // round-to-nearest-even
  return (unsigned short)(u >> 16);
}

// Lexicographic (score, idx) sorted-5 insert; prefers smaller idx on ties.
__device__ inline void insert5(float (&s)[5], int (&i5)[5], float sv, int jv) {
  if (sv < s[4] || (sv == s[4] && jv < i5[4])) {
    s[4] = sv; i5[4] = jv;
#pragma unroll
    for (int p = 4; p > 0; --p) {
      bool sw = (s[p] < s[p - 1]) || (s[p] == s[p - 1] && i5[p] < i5[p - 1]);
      if (sw) {
        float a = s[p]; s[p] = s[p - 1]; s[p - 1] = a;
        int   b = i5[p]; i5[p] = i5[p - 1]; i5[p - 1] = b;
      }
    }
  }
}

// Kernel 1: f32->bf16 convert, fp32 row sq-norms, zero output scalar.
__global__ __launch_bounds__(256) void prep_kernel(const float* __restrict__ x,
                                                   unsigned short* __restrict__ xb,
                                                   float* __restrict__ sq,
                                                   float* __restrict__ out) {
  const int wave = threadIdx.x >> 6, lane = threadIdx.x & 63;
  const int row = blockIdx.x * 4 + wave;
  const float2 v = ((const float2*)(x + (size_t)row * DD))[lane];
  float ss = v.x * v.x + v.y * v.y;
#pragma unroll
  for (int off = 32; off; off >>= 1) ss += __shfl_down(ss, off);
  if (lane == 0) sq[row] = ss;
  unsigned packed = (unsigned)f2bf(v.x) | ((unsigned)f2bf(v.y) << 16);
  ((unsigned*)(xb + (size_t)row * DD))[lane] = packed;
  if (blockIdx.x == 0 && threadIdx.x == 0) out[0] = 0.0f;
}

// Kernel 2: bf16-MFMA score tiles with in-register streaming top-5.
// Block = 64 rows x 1024 cols; grid (128, 8) = 1024 blocks (4/CU).
// __launch_bounds__(256,4): 128-VGPR budget -> no scratch spills (round-2 bug:
// VGPR_Count=56 forced ts/ti/afrag/stg to scratch -> 115 MB WRITE_SIZE).
// Single LDS buffer: stg[] registers are the second pipeline stage; the two
// barriers per tile make one buffer correct.
__global__ __launch_bounds__(256, 4) void dist_topk_kernel(
    const unsigned short* __restrict__ xb, const float* __restrict__ sq,
    float* __restrict__ pscore, unsigned short* __restrict__ pidx) {
  const int t = threadIdx.x;
  const int wave = t >> 6, lane = t & 63;
  const int lrow = lane & 15, lquad = lane >> 4;
  const int rowBase = blockIdx.x * 64;
  const int chunk = blockIdx.y;
  const int j0 = chunk * CPC;

  __shared__ unsigned short colsB[64 * DD];   // 16 KB, XOR-swizzled 16B chunks
  __shared__ float sqs[64];

  // A fragments: lane holds A[m=lane&15][k=(lane>>4)*8 + j], j=0..7
  const int arow = rowBase + wave * 16 + lrow;
  bf16x8 afrag[4];
  {
    const unsigned short* aptr = xb + (size_t)arow * DD + lquad * 8;
#pragma unroll
    for (int s = 0; s < 4; ++s) afrag[s] = *(const bf16x8*)(aptr + s * 32);
  }

  // Per-lane top-5 lists for 4 rows (rows wave*16 + lquad*4 + r).
  float ts[4][5]; int ti[4][5];
#pragma unroll
  for (int r = 0; r < 4; ++r)
#pragma unroll
    for (int k = 0; k < 5; ++k) { ts[r][k] = 3.0e38f; ti[r][k] = 0x7FFFFFFF; }

  // Prefetch tile 0 into registers.
  float4 stg[4];
  float sqv = 0.0f;
  {
    const float4* srcv = (const float4*)(xb + (size_t)j0 * DD);
#pragma unroll
    for (int i = 0; i < 4; ++i) stg[i] = srcv[t + i * 256];
    if (t < 64) sqv = sq[j0 + t];
  }

  for (int it = 0; it < TILES; ++it) {
    const int jt = j0 + it * 64;
    // Commit staged tile to LDS (XOR swizzle: chunk ch of row r -> ch^(r&15)).
    {
      float4* dstv = (float4*)colsB;
#pragma unroll
      for (int i = 0; i < 4; ++i) {
        int g = t + i * 256;
        int r = g >> 4, ch = g & 15;
        dstv[(r << 4) | (ch ^ (r & 15))] = stg[i];
      }
      if (t < 64) sqs[t] = sqv;
    }
    __syncthreads();

    // Prefetch next tile (overlaps with compute below; no LDS dependence).
    if (it + 1 < TILES) {
      const float4* srcv = (const float4*)(xb + (size_t)(jt + 64) * DD);
#pragma unroll
      for (int i = 0; i < 4; ++i) stg[i] = srcv[t + i * 256];
      if (t < 64) sqv = sq[jt + 64 + t];
    }

    // Compute 64x64 scores; select in-register from accumulator.
#pragma unroll
    for (int ct = 0; ct < 4; ++ct) {
      const unsigned short* bb = &colsB[(ct * 16 + lrow) * DD];
      bf16x8 bfr[4];
#pragma unroll
      for (int s = 0; s < 4; ++s)
        bfr[s] = *(const bf16x8*)(bb + ((((s << 2) + lquad) ^ lrow) << 3));
      f32x4 acc = {0.f, 0.f, 0.f, 0.f};
#pragma unroll
      for (int s = 0; s < 4; ++s)
        acc = __builtin_amdgcn_mfma_f32_16x16x32_bf16(afrag[s], bfr[s], acc, 0, 0, 0);
      // D layout: col = lane&15, row = (lane>>4)*4 + reg
      const int col = jt + ct * 16 + lrow;
      const float sqc = sqs[ct * 16 + lrow];
#pragma unroll
      for (int r = 0; r < 4; ++r)
        insert5(ts[r], ti[r], sqc - 2.0f * acc[r], col);
    }
    __syncthreads();   // all waves done reading colsB before next commit
  }

  // Merge across the 16 lanes (same lquad share rows) via xor-shuffles.
#pragma unroll
  for (int r = 0; r < 4; ++r) {
#pragma unroll
    for (int m = 1; m < 16; m <<= 1) {
      float os[5]; int oi[5];
#pragma unroll
      for (int k = 0; k < 5; ++k) {
        os[k] = __shfl_xor(ts[r][k], m);
        oi[k] = __shfl_xor(ti[r][k], m);
      }
#pragma unroll
      for (int k = 0; k < 5; ++k) insert5(ts[r], ti[r], os[k], oi[k]);
    }
  }
  if (lrow == 0) {
    const int row0 = rowBase + wave * 16 + lquad * 4;
#pragma unroll
    for (int r = 0; r < 4; ++r) {
      const size_t base = ((size_t)chunk * NN + row0 + r) * 5;
#pragma unroll
      for (int k = 0; k < 5; ++k) {
        pscore[base + k] = ts[r][k];
        pidx[base + k] = (unsigned short)ti[r][k];
      }
    }
  }
}

// Kernel 3: fused chunk-merge + exact fp32 hinge + mean.
// 64 blocks x 4 waves x 32 rows/wave; parallel 8-lane chunk merge; 1 atomic/block.
__global__ __launch_bounds__(256) void final_kernel(const float* __restrict__ x,
                                                    const float* __restrict__ pos,
                                                    const float* __restrict__ pscore,
                                                    const unsigned short* __restrict__ pidx,
                                                    float* __restrict__ out) {
  const int wave = threadIdx.x >> 6, lane = threadIdx.x & 63;
  float hsum = 0.0f;

  for (int it = 0; it < 32; ++it) {
    const int row = (blockIdx.x * 4 + wave) * 32 + it;

    // Parallel merge: lanes 0..7 each load one chunk's sorted-5 list.
    float fs[5]; int fi[5];
#pragma unroll
    for (int k = 0; k < 5; ++k) { fs[k] = 3.0e38f; fi[k] = 0x7FFFFFFF; }
    if (lane < CH) {
      const size_t base = ((size_t)lane * NN + row) * 5;
#pragma unroll
      for (int k = 0; k < 5; ++k)
        insert5(fs, fi, pscore[base + k], (int)pidx[base + k]);
    }
#pragma unroll
    for (int m = 1; m < CH; m <<= 1) {
      float os[5]; int oi[5];
#pragma unroll
      for (int k = 0; k < 5; ++k) {
        os[k] = __shfl_xor(fs[k], m);
        oi[k] = __shfl_xor(fi[k], m);
      }
#pragma unroll
      for (int k = 0; k < 5; ++k) insert5(fs, fi, os[k], oi[k]);
    }
    const int nidx = __shfl(fi[4], 0);

    const float2 xv  = ((const float2*)(x   + (size_t)row  * DD))[lane];
    const float2 pv  = ((const float2*)(pos + (size_t)row  * DD))[lane];
    const float2 nvv = ((const float2*)(x   + (size_t)nidx * DD))[lane];
    float a0 = xv.x - pv.x + 1e-6f, a1 = xv.y - pv.y + 1e-6f;
    float b0 = xv.x - nvv.x + 1e-6f, b1 = xv.y - nvv.y + 1e-6f;
    float dap = a0 * a0 + a1 * a1;
    float dan = b0 * b0 + b1 * b1;
#pragma unroll
    for (int off = 32; off; off >>= 1) {
      dap += __shfl_down(dap, off);
      dan += __shfl_down(dan, off);
    }
    if (lane == 0) hsum += fmaxf(sqrtf(dap) - sqrtf(dan) + 0.3f, 0.0f);
  }

  __shared__ float hs[4];
  if (lane == 0) hs[wave] = hsum;
  __syncthreads();
  if (threadIdx.x == 0) {
    float s = hs[0] + hs[1] + hs[2] + hs[3];
    atomicAdd(out, s * (1.0f / 8192.0f));
  }
}

extern "C" void kernel_launch(void* const* d_in, const int* in_sizes, int n_in,
                              void* d_out, int out_size, void* d_ws, size_t ws_size,
                              hipStream_t stream) {
  const float* x   = (const float*)d_in[0];
  const float* pos = (const float*)d_in[1];
  float* out = (float*)d_out;

  char* w = (char*)d_ws;
  unsigned short* xb = (unsigned short*)w;                       // 2 MB
  float* sq = (float*)(w + (size_t)NN * DD * 2);                 // 32 KB
  char* w2 = w + (size_t)NN * DD * 2 + (size_t)NN * 4;
  float* pscore = (float*)w2;                                    // CH*NN*5*4 = 1.31 MB
  unsigned short* pidx = (unsigned short*)(w2 + (size_t)CH * NN * 5 * 4);  // 0.66 MB

  prep_kernel<<<NN / 4, 256, 0, stream>>>(x, xb, sq, out);
  dist_topk_kernel<<<dim3(NN / 64, CH), 256, 0, stream>>>(xb, sq, pscore, pidx);
  final_kernel<<<64, 256, 0, stream>>>(x, pos, pscore, pidx, out);
}

// Round 4
// 166.740 us; speedup vs baseline: 2.7934x; 2.7934x over previous
//
#include <hip/hip_runtime.h>

#define NN 8192
#define DD 128
#define CH 8            // column chunks
#define CPC (NN / CH)   // cols per chunk = 1024
#define TILES (CPC / 64)
#define NPART 128       // partial-sum bins

typedef __bf16 bf16x8 __attribute__((ext_vector_type(8)));
typedef float f32x4 __attribute__((ext_vector_type(4)));

__device__ inline unsigned short f2bf(float f) {
  unsigned u = __float_as_uint(f);
  u += 0x7FFFu + ((u >> 16) & 1u);   // round-to-nearest-even
  return (unsigned short)(u >> 16);
}

// Streaming insert: strict-< on score only. The per-lane candidate stream
// arrives in strictly increasing col order, so equal scores keep the
// earlier (smaller) index automatically — exact tie-break without compares.
__device__ inline void insert5s(float (&s)[5], int (&i5)[5], float sv, int jv) {
  if (sv < s[4]) {
    s[4] = sv; i5[4] = jv;
#pragma unroll
    for (int p = 4; p > 0; --p) {
      if (s[p] < s[p - 1]) {
        float a = s[p]; s[p] = s[p - 1]; s[p - 1] = a;
        int   b = i5[p]; i5[p] = i5[p - 1]; i5[p - 1] = b;
      }
    }
  }
}

// Lexicographic (score, idx) insert for cross-lane/cross-chunk merges.
__device__ inline void insert5x(float (&s)[5], int (&i5)[5], float sv, int jv) {
  if (sv < s[4] || (sv == s[4] && jv < i5[4])) {
    s[4] = sv; i5[4] = jv;
#pragma unroll
    for (int p = 4; p > 0; --p) {
      bool sw = (s[p] < s[p - 1]) || (s[p] == s[p - 1] && i5[p] < i5[p - 1]);
      if (sw) {
        float a = s[p]; s[p] = s[p - 1]; s[p - 1] = a;
        int   b = i5[p]; i5[p] = i5[p - 1]; i5[p - 1] = b;
      }
    }
  }
}

// Kernel 1: f32->bf16 convert, fp32 row sq-norms, zero partial bins.
__global__ __launch_bounds__(256) void prep_kernel(const float* __restrict__ x,
                                                   unsigned short* __restrict__ xb,
                                                   float* __restrict__ sq,
                                                   float* __restrict__ partial) {
  const int wave = threadIdx.x >> 6, lane = threadIdx.x & 63;
  const int row = blockIdx.x * 4 + wave;
  const float2 v = ((const float2*)(x + (size_t)row * DD))[lane];
  float ss = v.x * v.x + v.y * v.y;
#pragma unroll
  for (int off = 32; off; off >>= 1) ss += __shfl_down(ss, off);
  if (lane == 0) sq[row] = ss;
  unsigned packed = (unsigned)f2bf(v.x) | ((unsigned)f2bf(v.y) << 16);
  ((unsigned*)(xb + (size_t)row * DD))[lane] = packed;
  if (blockIdx.x == 0 && threadIdx.x < NPART) partial[threadIdx.x] = 0.0f;
}

// Kernel 2: bf16-MFMA score tiles + in-register streaming top-5.
// SWAPPED operand order: D = Sc^T, so lane = ONE row (lane&15), reg = candidate.
// Per-lane top-5 state is 10 VGPRs (was 40 -> spilled). Double-buffered LDS,
// ONE barrier per tile. Grid (128, 8) = 1024 blocks = 4/CU.
__global__ __launch_bounds__(256, 4) void dist_topk_kernel(
    const unsigned short* __restrict__ xb, const float* __restrict__ sq,
    float* __restrict__ pscore, unsigned short* __restrict__ pidx) {
  const int t = threadIdx.x;
  const int wave = t >> 6, lane = t & 63;
  const int lrow = lane & 15, lquad = lane >> 4;
  const int rowBase = blockIdx.x * 64;
  const int chunk = blockIdx.y;
  const int j0 = chunk * CPC;

  __shared__ unsigned short colsB[2][64 * DD];   // 2 x 16 KB, XOR-swizzled 16B chunks
  __shared__ float sqs[2][64];

  // Our-row fragments (used as MFMA B-operand): lane holds X[row][k=lquad*8+j].
  const int myrow = rowBase + wave * 16 + lrow;
  bf16x8 afrag[4];
  {
    const unsigned short* aptr = xb + (size_t)myrow * DD + lquad * 8;
#pragma unroll
    for (int s = 0; s < 4; ++s) afrag[s] = *(const bf16x8*)(aptr + s * 32);
  }

  // Top-5 for ONE row (myrow) per lane.
  float ts[5]; int ti[5];
#pragma unroll
  for (int k = 0; k < 5; ++k) { ts[k] = 3.0e38f; ti[k] = 0x7FFFFFFF; }

  // Prefetch tile 0 into registers.
  float4 stg[4];
  float sqv = 0.0f;
  {
    const float4* srcv = (const float4*)(xb + (size_t)j0 * DD);
#pragma unroll
    for (int i = 0; i < 4; ++i) stg[i] = srcv[t + i * 256];
    if (t < 64) sqv = sq[j0 + t];
  }

  for (int it = 0; it < TILES; ++it) {
    const int jt = j0 + it * 64;
    const int cur = it & 1;
    // Commit staged tile (XOR swizzle: chunk ch of row r -> ch^(r&15)).
    {
      float4* dstv = (float4*)colsB[cur];
#pragma unroll
      for (int i = 0; i < 4; ++i) {
        int g = t + i * 256;
        int r = g >> 4, ch = g & 15;
        dstv[(r << 4) | (ch ^ (r & 15))] = stg[i];
      }
      if (t < 64) sqs[cur][t] = sqv;
    }
    // Prefetch next tile (global loads in flight across the barrier).
    if (it + 1 < TILES) {
      const float4* srcv = (const float4*)(xb + (size_t)(jt + 64) * DD);
#pragma unroll
      for (int i = 0; i < 4; ++i) stg[i] = srcv[t + i * 256];
      if (t < 64) sqv = sq[jt + 64 + t];
    }
    __syncthreads();

#pragma unroll
    for (int ct = 0; ct < 4; ++ct) {
      const unsigned short* bb = &colsB[cur][(ct * 16 + lrow) * DD];
      bf16x8 bfr[4];
#pragma unroll
      for (int s = 0; s < 4; ++s)
        bfr[s] = *(const bf16x8*)(bb + ((((s << 2) + lquad) ^ lrow) << 3));
      f32x4 acc = {0.f, 0.f, 0.f, 0.f};
#pragma unroll
      for (int s = 0; s < 4; ++s)
        acc = __builtin_amdgcn_mfma_f32_16x16x32_bf16(bfr[s], afrag[s], acc, 0, 0, 0);
      // D = Sc^T: reg r -> candidate col ct*16 + lquad*4 + r; lane col -> myrow.
      const f32x4 sq4 = *(const f32x4*)&sqs[cur][ct * 16 + lquad * 4];
      const int colb = jt + ct * 16 + lquad * 4;
#pragma unroll
      for (int r = 0; r < 4; ++r)
        insert5s(ts, ti, sq4[r] - 2.0f * acc[r], colb + r);
    }
    // no second barrier: next commit targets the other buffer; barrier(it+1)
    // orders it against this iteration's reads.
  }

  // Merge across lquads (lanes r, r+16, r+32, r+48 hold row r's partials).
#pragma unroll
  for (int m = 16; m < 64; m <<= 1) {
    float os[5]; int oi[5];
#pragma unroll
    for (int k = 0; k < 5; ++k) {
      os[k] = __shfl_xor(ts[k], m);
      oi[k] = __shfl_xor(ti[k], m);
    }
#pragma unroll
    for (int k = 0; k < 5; ++k) insert5x(ts, ti, os[k], oi[k]);
  }
  if (lquad == 0) {
    const size_t base = ((size_t)chunk * NN + myrow) * 5;
#pragma unroll
    for (int k = 0; k < 5; ++k) {
      pscore[base + k] = ts[k];
      pidx[base + k] = (unsigned short)ti[k];
    }
  }
}

// Kernel 3: one row per WAVE (2048 blocks): parallel 8-lane chunk merge ->
// neg idx -> exact fp32 hinge; block partial -> 128 atomic bins.
__global__ __launch_bounds__(256) void final_kernel(const float* __restrict__ x,
                                                    const float* __restrict__ pos,
                                                    const float* __restrict__ pscore,
                                                    const unsigned short* __restrict__ pidx,
                                                    float* __restrict__ partial) {
  const int wave = threadIdx.x >> 6, lane = threadIdx.x & 63;
  const int row = blockIdx.x * 4 + wave;

  float fs[5]; int fi[5];
#pragma unroll
  for (int k = 0; k < 5; ++k) { fs[k] = 3.0e38f; fi[k] = 0x7FFFFFFF; }
  if (lane < CH) {
    const size_t base = ((size_t)lane * NN + row) * 5;
#pragma unroll
    for (int k = 0; k < 5; ++k)
      insert5x(fs, fi, pscore[base + k], (int)pidx[base + k]);
  }
#pragma unroll
  for (int m = 1; m < CH; m <<= 1) {
    float os[5]; int oi[5];
#pragma unroll
    for (int k = 0; k < 5; ++k) {
      os[k] = __shfl_xor(fs[k], m);
      oi[k] = __shfl_xor(fi[k], m);
    }
#pragma unroll
    for (int k = 0; k < 5; ++k) insert5x(fs, fi, os[k], oi[k]);
  }
  const int nidx = __shfl(fi[4], 0);

  const float2 xv  = ((const float2*)(x   + (size_t)row  * DD))[lane];
  const float2 pv  = ((const float2*)(pos + (size_t)row  * DD))[lane];
  const float2 nvv = ((const float2*)(x   + (size_t)nidx * DD))[lane];
  float a0 = xv.x - pv.x + 1e-6f, a1 = xv.y - pv.y + 1e-6f;
  float b0 = xv.x - nvv.x + 1e-6f, b1 = xv.y - nvv.y + 1e-6f;
  float dap = a0 * a0 + a1 * a1;
  float dan = b0 * b0 + b1 * b1;
#pragma unroll
  for (int off = 32; off; off >>= 1) {
    dap += __shfl_down(dap, off);
    dan += __shfl_down(dan, off);
  }
  __shared__ float hs[4];
  if (lane == 0) hs[wave] = fmaxf(sqrtf(dap) - sqrtf(dan) + 0.3f, 0.0f);
  __syncthreads();
  if (threadIdx.x == 0) {
    float s = hs[0] + hs[1] + hs[2] + hs[3];
    atomicAdd(&partial[blockIdx.x & (NPART - 1)], s);
  }
}

// Kernel 4: sum the 128 partial bins -> mean.
__global__ __launch_bounds__(64) void reduce_kernel(const float* __restrict__ partial,
                                                    float* __restrict__ out) {
  float v = partial[threadIdx.x] + partial[threadIdx.x + 64];
#pragma unroll
  for (int off = 32; off; off >>= 1) v += __shfl_down(v, off);
  if (threadIdx.x == 0) out[0] = v * (1.0f / 8192.0f);
}

extern "C" void kernel_launch(void* const* d_in, const int* in_sizes, int n_in,
                              void* d_out, int out_size, void* d_ws, size_t ws_size,
                              hipStream_t stream) {
  const float* x   = (const float*)d_in[0];
  const float* pos = (const float*)d_in[1];
  float* out = (float*)d_out;

  char* w = (char*)d_ws;
  unsigned short* xb = (unsigned short*)w;                       // 2 MB
  float* sq = (float*)(w + (size_t)NN * DD * 2);                 // 32 KB
  char* w2 = w + (size_t)NN * DD * 2 + (size_t)NN * 4;
  float* pscore = (float*)w2;                                    // CH*NN*5*4 = 1.31 MB
  unsigned short* pidx = (unsigned short*)(w2 + (size_t)CH * NN * 5 * 4);  // 0.66 MB
  float* partial = (float*)(w2 + (size_t)CH * NN * 5 * 6);       // 512 B

  prep_kernel<<<NN / 4, 256, 0, stream>>>(x, xb, sq, partial);
  dist_topk_kernel<<<dim3(NN / 64, CH), 256, 0, stream>>>(xb, sq, pscore, pidx);
  final_kernel<<<NN / 4, 256, 0, stream>>>(x, pos, pscore, pidx, partial);
  reduce_kernel<<<1, 64, 0, stream>>>(partial, out);
}

// Round 5
// 136.001 us; speedup vs baseline: 3.4248x; 1.2260x over previous
//
#include <hip/hip_runtime.h>

#define NN 8192
#define DD 128
#define CH 8            // column chunks
#define CPC (NN / CH)   // cols per chunk = 1024
#define TILES (CPC / 64)
#define NPART 128       // partial-sum bins

typedef __bf16 bf16x8 __attribute__((ext_vector_type(8)));
typedef float f32x4 __attribute__((ext_vector_type(4)));

__device__ inline unsigned short f2bf(float f) {
  unsigned u = __float_as_uint(f);
  u += 0x7FFFu + ((u >> 16) & 1u);   // round-to-nearest-even
  return (unsigned short)(u >> 16);
}

// Streaming insert on NAMED scalars (no arrays -> guaranteed VGPR promotion).
// Strict-< : per-lane candidate stream is ascending in col, so equal scores
// keep the earlier (smaller) index automatically. Straight-line shift-down:
// position k takes old k-1 if the new value lands above it.
__device__ __attribute__((always_inline)) inline void ins5s(
    float& s0, float& s1, float& s2, float& s3, float& s4,
    int& i0, int& i1, int& i2, int& i3, int& i4, float v, int j) {
  if (v < s4) {
    bool b0 = v < s0, b1 = v < s1, b2 = v < s2, b3 = v < s3;
    s4 = b3 ? s3 : v;              i4 = b3 ? i3 : j;
    s3 = b3 ? (b2 ? s2 : v) : s3;  i3 = b3 ? (b2 ? i2 : j) : i3;
    s2 = b2 ? (b1 ? s1 : v) : s2;  i2 = b2 ? (b1 ? i1 : j) : i2;
    s1 = b1 ? (b0 ? s0 : v) : s1;  i1 = b1 ? (b0 ? i0 : j) : i1;
    s0 = b0 ? v : s0;              i0 = b0 ? j : i0;
  }
}

// Lexicographic (score, idx) insert for cross-lane / cross-chunk merges.
__device__ __attribute__((always_inline)) inline void ins5x(
    float& s0, float& s1, float& s2, float& s3, float& s4,
    int& i0, int& i1, int& i2, int& i3, int& i4, float v, int j) {
  if (v < s4 || (v == s4 && j < i4)) {
    bool b0 = v < s0 || (v == s0 && j < i0);
    bool b1 = v < s1 || (v == s1 && j < i1);
    bool b2 = v < s2 || (v == s2 && j < i2);
    bool b3 = v < s3 || (v == s3 && j < i3);
    s4 = b3 ? s3 : v;              i4 = b3 ? i3 : j;
    s3 = b3 ? (b2 ? s2 : v) : s3;  i3 = b3 ? (b2 ? i2 : j) : i3;
    s2 = b2 ? (b1 ? s1 : v) : s2;  i2 = b2 ? (b1 ? i1 : j) : i2;
    s1 = b1 ? (b0 ? s0 : v) : s1;  i1 = b1 ? (b0 ? i0 : j) : i1;
    s0 = b0 ? v : s0;              i0 = b0 ? j : i0;
  }
}

// Kernel 1: f32->bf16 convert, fp32 row sq-norms, zero partial bins.
__global__ __launch_bounds__(256) void prep_kernel(const float* __restrict__ x,
                                                   unsigned short* __restrict__ xb,
                                                   float* __restrict__ sq,
                                                   float* __restrict__ partial) {
  const int wave = threadIdx.x >> 6, lane = threadIdx.x & 63;
  const int row = blockIdx.x * 4 + wave;
  const float2 v = ((const float2*)(x + (size_t)row * DD))[lane];
  float ss = v.x * v.x + v.y * v.y;
#pragma unroll
  for (int off = 32; off; off >>= 1) ss += __shfl_down(ss, off);
  if (lane == 0) sq[row] = ss;
  unsigned packed = (unsigned)f2bf(v.x) | ((unsigned)f2bf(v.y) << 16);
  ((unsigned*)(xb + (size_t)row * DD))[lane] = packed;
  if (blockIdx.x == 0 && threadIdx.x < NPART) partial[threadIdx.x] = 0.0f;
}

// Kernel 2: bf16-MFMA score tiles + in-register streaming top-5.
// Swapped MFMA operands: D = Sc^T (lane = one row, reg = candidate).
// ALL hot state in named scalars — rounds 2-4 showed indexed per-thread
// arrays stayed in scratch (VGPR=52, WRITE_SIZE~103MB) regardless of
// launch-bounds budget.
__global__ __launch_bounds__(256, 4) void dist_topk_kernel(
    const unsigned short* __restrict__ xb, const float* __restrict__ sq,
    float* __restrict__ pscore, unsigned short* __restrict__ pidx) {
  const int t = threadIdx.x;
  const int wave = t >> 6, lane = t & 63;
  const int lrow = lane & 15, lquad = lane >> 4;
  const int rowBase = blockIdx.x * 64;
  const int chunk = blockIdx.y;
  const int j0 = chunk * CPC;

  __shared__ unsigned short colsB[2][64 * DD];   // 2 x 16 KB, XOR-swizzled 16B chunks
  __shared__ float sqs[2][64];

  // My-row fragments (MFMA B-operand): lane holds X[myrow][k = lquad*8 + j].
  const int myrow = rowBase + wave * 16 + lrow;
  const unsigned short* aptr = xb + (size_t)myrow * DD + lquad * 8;
  bf16x8 a0 = *(const bf16x8*)(aptr);
  bf16x8 a1 = *(const bf16x8*)(aptr + 32);
  bf16x8 a2 = *(const bf16x8*)(aptr + 64);
  bf16x8 a3 = *(const bf16x8*)(aptr + 96);

  // Top-5 for ONE row per lane — named scalars.
  float s0 = 3.0e38f, s1 = 3.0e38f, s2 = 3.0e38f, s3 = 3.0e38f, s4 = 3.0e38f;
  int i0 = 0x7FFFFFFF, i1 = 0x7FFFFFFF, i2 = 0x7FFFFFFF, i3 = 0x7FFFFFFF,
      i4 = 0x7FFFFFFF;

  // Staging: thread t carries fragments g = t + i*256 (r = g>>4, ch = g&15).
  // Swizzled dst = (r<<4) | (ch ^ (r&15)); since (r+16i)&15 == r&15, the four
  // destinations are dst0 + i*256 (float4 units).
  const int sr = t >> 4, sch = t & 15;
  const int dst0 = (sr << 4) | (sch ^ (sr & 15));

  // Prefetch tile 0.
  const float4* srcv = (const float4*)(xb + (size_t)j0 * DD);
  float4 g0 = srcv[t], g1 = srcv[t + 256], g2 = srcv[t + 512], g3 = srcv[t + 768];
  float sqv = 0.0f;
  if (t < 64) sqv = sq[j0 + t];

  for (int it = 0; it < TILES; ++it) {
    const int jt = j0 + it * 64;
    const int cur = it & 1;
    {
      float4* dstv = (float4*)colsB[cur];
      dstv[dst0] = g0;
      dstv[dst0 + 256] = g1;
      dstv[dst0 + 512] = g2;
      dstv[dst0 + 768] = g3;
      if (t < 64) sqs[cur][t] = sqv;
    }
    // Prefetch next tile (in flight across the barrier).
    if (it + 1 < TILES) {
      const float4* nsrc = (const float4*)(xb + (size_t)(jt + 64) * DD);
      g0 = nsrc[t]; g1 = nsrc[t + 256]; g2 = nsrc[t + 512]; g3 = nsrc[t + 768];
      if (t < 64) sqv = sq[jt + 64 + t];
    }
    __syncthreads();

#pragma unroll
    for (int ct = 0; ct < 4; ++ct) {
      const unsigned short* bb = &colsB[cur][(ct * 16 + lrow) * DD];
      bf16x8 b0 = *(const bf16x8*)(bb + (((0 + lquad) ^ lrow) << 3));
      bf16x8 b1 = *(const bf16x8*)(bb + (((4 + lquad) ^ lrow) << 3));
      bf16x8 b2 = *(const bf16x8*)(bb + (((8 + lquad) ^ lrow) << 3));
      bf16x8 b3 = *(const bf16x8*)(bb + (((12 + lquad) ^ lrow) << 3));
      f32x4 acc = {0.f, 0.f, 0.f, 0.f};
      acc = __builtin_amdgcn_mfma_f32_16x16x32_bf16(b0, a0, acc, 0, 0, 0);
      acc = __builtin_amdgcn_mfma_f32_16x16x32_bf16(b1, a1, acc, 0, 0, 0);
      acc = __builtin_amdgcn_mfma_f32_16x16x32_bf16(b2, a2, acc, 0, 0, 0);
      acc = __builtin_amdgcn_mfma_f32_16x16x32_bf16(b3, a3, acc, 0, 0, 0);
      // D = Sc^T: reg r -> candidate col ct*16 + lquad*4 + r; lane -> myrow.
      const f32x4 sq4 = *(const f32x4*)&sqs[cur][ct * 16 + lquad * 4];
      const int colb = jt + ct * 16 + lquad * 4;
      ins5s(s0, s1, s2, s3, s4, i0, i1, i2, i3, i4, sq4[0] - 2.0f * acc[0], colb);
      ins5s(s0, s1, s2, s3, s4, i0, i1, i2, i3, i4, sq4[1] - 2.0f * acc[1], colb + 1);
      ins5s(s0, s1, s2, s3, s4, i0, i1, i2, i3, i4, sq4[2] - 2.0f * acc[2], colb + 2);
      ins5s(s0, s1, s2, s3, s4, i0, i1, i2, i3, i4, sq4[3] - 2.0f * acc[3], colb + 3);
    }
    // Single barrier per tile: next commit targets the other buffer and is
    // ordered against this iteration's reads by barrier(it+1).
  }

  // Merge across lquads (lanes r, r+16, r+32, r+48 hold row r's partials).
#pragma unroll
  for (int m = 16; m < 64; m <<= 1) {
    float o0 = __shfl_xor(s0, m), o1 = __shfl_xor(s1, m), o2 = __shfl_xor(s2, m),
          o3 = __shfl_xor(s3, m), o4 = __shfl_xor(s4, m);
    int p0 = __shfl_xor(i0, m), p1 = __shfl_xor(i1, m), p2 = __shfl_xor(i2, m),
        p3 = __shfl_xor(i3, m), p4 = __shfl_xor(i4, m);
    ins5x(s0, s1, s2, s3, s4, i0, i1, i2, i3, i4, o0, p0);
    ins5x(s0, s1, s2, s3, s4, i0, i1, i2, i3, i4, o1, p1);
    ins5x(s0, s1, s2, s3, s4, i0, i1, i2, i3, i4, o2, p2);
    ins5x(s0, s1, s2, s3, s4, i0, i1, i2, i3, i4, o3, p3);
    ins5x(s0, s1, s2, s3, s4, i0, i1, i2, i3, i4, o4, p4);
  }
  if (lquad == 0) {
    const size_t base = ((size_t)chunk * NN + myrow) * 5;
    pscore[base + 0] = s0; pidx[base + 0] = (unsigned short)i0;
    pscore[base + 1] = s1; pidx[base + 1] = (unsigned short)i1;
    pscore[base + 2] = s2; pidx[base + 2] = (unsigned short)i2;
    pscore[base + 3] = s3; pidx[base + 3] = (unsigned short)i3;
    pscore[base + 4] = s4; pidx[base + 4] = (unsigned short)i4;
  }
}

// Kernel 3: one row per wave: parallel 8-lane chunk merge -> neg idx ->
// exact fp32 hinge; block partial -> 128 atomic bins.
__global__ __launch_bounds__(256) void final_kernel(const float* __restrict__ x,
                                                    const float* __restrict__ pos,
                                                    const float* __restrict__ pscore,
                                                    const unsigned short* __restrict__ pidx,
                                                    float* __restrict__ partial) {
  const int wave = threadIdx.x >> 6, lane = threadIdx.x & 63;
  const int row = blockIdx.x * 4 + wave;

  float s0 = 3.0e38f, s1 = 3.0e38f, s2 = 3.0e38f, s3 = 3.0e38f, s4 = 3.0e38f;
  int i0 = 0x7FFFFFFF, i1 = 0x7FFFFFFF, i2 = 0x7FFFFFFF, i3 = 0x7FFFFFFF,
      i4 = 0x7FFFFFFF;
  if (lane < CH) {
    const size_t base = ((size_t)lane * NN + row) * 5;
    ins5x(s0, s1, s2, s3, s4, i0, i1, i2, i3, i4, pscore[base + 0], (int)pidx[base + 0]);
    ins5x(s0, s1, s2, s3, s4, i0, i1, i2, i3, i4, pscore[base + 1], (int)pidx[base + 1]);
    ins5x(s0, s1, s2, s3, s4, i0, i1, i2, i3, i4, pscore[base + 2], (int)pidx[base + 2]);
    ins5x(s0, s1, s2, s3, s4, i0, i1, i2, i3, i4, pscore[base + 3], (int)pidx[base + 3]);
    ins5x(s0, s1, s2, s3, s4, i0, i1, i2, i3, i4, pscore[base + 4], (int)pidx[base + 4]);
  }
#pragma unroll
  for (int m = 1; m < CH; m <<= 1) {
    float o0 = __shfl_xor(s0, m), o1 = __shfl_xor(s1, m), o2 = __shfl_xor(s2, m),
          o3 = __shfl_xor(s3, m), o4 = __shfl_xor(s4, m);
    int p0 = __shfl_xor(i0, m), p1 = __shfl_xor(i1, m), p2 = __shfl_xor(i2, m),
        p3 = __shfl_xor(i3, m), p4 = __shfl_xor(i4, m);
    ins5x(s0, s1, s2, s3, s4, i0, i1, i2, i3, i4, o0, p0);
    ins5x(s0, s1, s2, s3, s4, i0, i1, i2, i3, i4, o1, p1);
    ins5x(s0, s1, s2, s3, s4, i0, i1, i2, i3, i4, o2, p2);
    ins5x(s0, s1, s2, s3, s4, i0, i1, i2, i3, i4, o3, p3);
    ins5x(s0, s1, s2, s3, s4, i0, i1, i2, i3, i4, o4, p4);
  }
  const int nidx = __shfl(i4, 0);

  const float2 xv  = ((const float2*)(x   + (size_t)row  * DD))[lane];
  const float2 pv  = ((const float2*)(pos + (size_t)row  * DD))[lane];
  const float2 nvv = ((const float2*)(x   + (size_t)nidx * DD))[lane];
  float a0 = xv.x - pv.x + 1e-6f, a1 = xv.y - pv.y + 1e-6f;
  float b0 = xv.x - nvv.x + 1e-6f, b1 = xv.y - nvv.y + 1e-6f;
  float dap = a0 * a0 + a1 * a1;
  float dan = b0 * b0 + b1 * b1;
#pragma unroll
  for (int off = 32; off; off >>= 1) {
    dap += __shfl_down(dap, off);
    dan += __shfl_down(dan, off);
  }
  __shared__ float hs[4];
  if (lane == 0) hs[wave] = fmaxf(sqrtf(dap) - sqrtf(dan) + 0.3f, 0.0f);
  __syncthreads();
  if (threadIdx.x == 0) {
    float s = hs[0] + hs[1] + hs[2] + hs[3];
    atomicAdd(&partial[blockIdx.x & (NPART - 1)], s);
  }
}

// Kernel 4: sum the 128 partial bins -> mean.
__global__ __launch_bounds__(64) void reduce_kernel(const float* __restrict__ partial,
                                                    float* __restrict__ out) {
  float v = partial[threadIdx.x] + partial[threadIdx.x + 64];
#pragma unroll
  for (int off = 32; off; off >>= 1) v += __shfl_down(v, off);
  if (threadIdx.x == 0) out[0] = v * (1.0f / 8192.0f);
}

extern "C" void kernel_launch(void* const* d_in, const int* in_sizes, int n_in,
                              void* d_out, int out_size, void* d_ws, size_t ws_size,
                              hipStream_t stream) {
  const float* x   = (const float*)d_in[0];
  const float* pos = (const float*)d_in[1];
  float* out = (float*)d_out;

  char* w = (char*)d_ws;
  unsigned short* xb = (unsigned short*)w;                       // 2 MB
  float* sq = (float*)(w + (size_t)NN * DD * 2);                 // 32 KB
  char* w2 = w + (size_t)NN * DD * 2 + (size_t)NN * 4;
  float* pscore = (float*)w2;                                    // CH*NN*5*4 = 1.31 MB
  unsigned short* pidx = (unsigned short*)(w2 + (size_t)CH * NN * 5 * 4);  // 0.66 MB
  float* partial = (float*)(w2 + (size_t)CH * NN * 5 * 6);       // 512 B

  prep_kernel<<<NN / 4, 256, 0, stream>>>(x, xb, sq, partial);
  dist_topk_kernel<<<dim3(NN / 64, CH), 256, 0, stream>>>(xb, sq, pscore, pidx);
  final_kernel<<<NN / 4, 256, 0, stream>>>(x, pos, pscore, pidx, partial);
  reduce_kernel<<<1, 64, 0, stream>>>(partial, out);
}

// Round 6
// 124.071 us; speedup vs baseline: 3.7541x; 1.0962x over previous
//
#include <hip/hip_runtime.h>

#define NN 8192
#define DD 128
#define CH 8            // column chunks
#define CPC (NN / CH)   // cols per chunk = 1024
#define TILES (CPC / 64)

typedef __bf16 bf16x8 __attribute__((ext_vector_type(8)));
typedef float f32x4 __attribute__((ext_vector_type(4)));

#define PACK_INIT __uint_as_float(0x7F7FFFFFu)

// Pack (score, idx): keep high 19 bits of the fp32 score, idx in low 13.
// Monotone bucket-quantization (quantum <= 0.125 for |s|<512); within a
// bucket, smaller idx = smaller float => min-network prefers smaller idx,
// matching reference top_k tie-breaking. Negative scores only occur for
// self (rank-1 by a huge margin), so the inverted idx order there is moot.
static __device__ __forceinline__ float packsi(float s, unsigned idx) {
  return __uint_as_float((__float_as_uint(s) & 0xFFFFE000u) | idx);
}

// Branchless sorted-5 insert (keep 5 smallest): 9 min/max ops, no divergence.
static __device__ __forceinline__ void net5(float& s0, float& s1, float& s2,
                                            float& s3, float& s4, float v) {
  float t1 = fmaxf(s0, v);  s0 = fminf(s0, v);
  float t2 = fmaxf(s1, t1); s1 = fminf(s1, t1);
  float t3 = fmaxf(s2, t2); s2 = fminf(s2, t2);
  float t4 = fmaxf(s3, t3); s3 = fminf(s3, t3);
  s4 = fminf(s4, t4);
}

static __device__ __forceinline__ unsigned short f2bf(float f) {
  unsigned u = __float_as_uint(f);
  u += 0x7FFFu + ((u >> 16) & 1u);   // round-to-nearest-even
  return (unsigned short)(u >> 16);
}

// Kernel 1: f32->bf16 convert, fp32 row sq-norms, zero output scalar.
__global__ __launch_bounds__(256) void prep_kernel(const float* __restrict__ x,
                                                   unsigned short* __restrict__ xb,
                                                   float* __restrict__ sq,
                                                   float* __restrict__ out) {
  const int wave = threadIdx.x >> 6, lane = threadIdx.x & 63;
  const int row = blockIdx.x * 4 + wave;
  const float2 v = ((const float2*)(x + (size_t)row * DD))[lane];
  float ss = v.x * v.x + v.y * v.y;
#pragma unroll
  for (int off = 32; off; off >>= 1) ss += __shfl_down(ss, off);
  if (lane == 0) sq[row] = ss;
  unsigned packed = (unsigned)f2bf(v.x) | ((unsigned)f2bf(v.y) << 16);
  ((unsigned*)(xb + (size_t)row * DD))[lane] = packed;
  if (blockIdx.x == 0 && threadIdx.x == 0) out[0] = 0.0f;
}

// Kernel 2: bf16-MFMA scores + branchless packed top-5.
// R=32 rows/wave via two 16-row groups sharing each candidate fragment
// (halves LDS reads per row). Block = 128 rows x 1024 cols; grid (64,8)
// = 512 blocks = 2/CU. launch_bounds(256,2): grid only gives 2 waves/SIMD,
// so allow 256 VGPRs -> no spill risk (round-2/4 lesson).
__global__ __launch_bounds__(256, 2) void dist_topk_kernel(
    const unsigned short* __restrict__ xb, const float* __restrict__ sq,
    float* __restrict__ pscore) {
  const int t = threadIdx.x;
  const int wave = t >> 6, lane = t & 63;
  const int lrow = lane & 15, lquad = lane >> 4;
  const int rowBase = blockIdx.x * 128;
  const int chunk = blockIdx.y;
  const int j0 = chunk * CPC;

  __shared__ unsigned short colsB[2][64 * DD];   // 2 x 16 KB, XOR-swizzled
  __shared__ float sqs[2][64];

  // My-row fragments (MFMA 2nd operand): lane holds X[row][k=lquad*8+j].
  const int myrow0 = rowBase + wave * 32 + lrow;
  const int myrow1 = myrow0 + 16;
  const unsigned short* ap0 = xb + (size_t)myrow0 * DD + lquad * 8;
  const unsigned short* ap1 = xb + (size_t)myrow1 * DD + lquad * 8;
  bf16x8 a00 = *(const bf16x8*)(ap0);
  bf16x8 a01 = *(const bf16x8*)(ap0 + 32);
  bf16x8 a02 = *(const bf16x8*)(ap0 + 64);
  bf16x8 a03 = *(const bf16x8*)(ap0 + 96);
  bf16x8 a10 = *(const bf16x8*)(ap1);
  bf16x8 a11 = *(const bf16x8*)(ap1 + 32);
  bf16x8 a12 = *(const bf16x8*)(ap1 + 64);
  bf16x8 a13 = *(const bf16x8*)(ap1 + 96);

  // Packed sorted-5 lists, one per row group, named scalars.
  float p00 = PACK_INIT, p01 = PACK_INIT, p02 = PACK_INIT, p03 = PACK_INIT,
        p04 = PACK_INIT;
  float p10 = PACK_INIT, p11 = PACK_INIT, p12 = PACK_INIT, p13 = PACK_INIT,
        p14 = PACK_INIT;

  // Staging closed-form swizzle (round-5 verified).
  const int sr = t >> 4, sch = t & 15;
  const int dst0 = (sr << 4) | (sch ^ (sr & 15));

  const float4* srcv = (const float4*)(xb + (size_t)j0 * DD);
  float4 g0 = srcv[t], g1 = srcv[t + 256], g2 = srcv[t + 512], g3 = srcv[t + 768];
  float sqv = 0.0f;
  if (t < 64) sqv = sq[j0 + t];

  for (int it = 0; it < TILES; ++it) {
    const int jt = j0 + it * 64;
    const int cur = it & 1;
    {
      float4* dstv = (float4*)colsB[cur];
      dstv[dst0] = g0;
      dstv[dst0 + 256] = g1;
      dstv[dst0 + 512] = g2;
      dstv[dst0 + 768] = g3;
      if (t < 64) sqs[cur][t] = sqv;
    }
    if (it + 1 < TILES) {
      const float4* nsrc = (const float4*)(xb + (size_t)(jt + 64) * DD);
      g0 = nsrc[t]; g1 = nsrc[t + 256]; g2 = nsrc[t + 512]; g3 = nsrc[t + 768];
      if (t < 64) sqv = sq[jt + 64 + t];
    }
    __syncthreads();

#pragma unroll
    for (int ct = 0; ct < 4; ++ct) {
      const unsigned short* bb = &colsB[cur][(ct * 16 + lrow) * DD];
      bf16x8 b0 = *(const bf16x8*)(bb + (((0 + lquad) ^ lrow) << 3));
      bf16x8 b1 = *(const bf16x8*)(bb + (((4 + lquad) ^ lrow) << 3));
      bf16x8 b2 = *(const bf16x8*)(bb + (((8 + lquad) ^ lrow) << 3));
      bf16x8 b3 = *(const bf16x8*)(bb + (((12 + lquad) ^ lrow) << 3));
      f32x4 acc0 = {0.f, 0.f, 0.f, 0.f};
      f32x4 acc1 = {0.f, 0.f, 0.f, 0.f};
      acc0 = __builtin_amdgcn_mfma_f32_16x16x32_bf16(b0, a00, acc0, 0, 0, 0);
      acc1 = __builtin_amdgcn_mfma_f32_16x16x32_bf16(b0, a10, acc1, 0, 0, 0);
      acc0 = __builtin_amdgcn_mfma_f32_16x16x32_bf16(b1, a01, acc0, 0, 0, 0);
      acc1 = __builtin_amdgcn_mfma_f32_16x16x32_bf16(b1, a11, acc1, 0, 0, 0);
      acc0 = __builtin_amdgcn_mfma_f32_16x16x32_bf16(b2, a02, acc0, 0, 0, 0);
      acc1 = __builtin_amdgcn_mfma_f32_16x16x32_bf16(b2, a12, acc1, 0, 0, 0);
      acc0 = __builtin_amdgcn_mfma_f32_16x16x32_bf16(b3, a03, acc0, 0, 0, 0);
      acc1 = __builtin_amdgcn_mfma_f32_16x16x32_bf16(b3, a13, acc1, 0, 0, 0);
      // D = Sc^T: reg r -> cand ct*16 + lquad*4 + r; lane -> myrow.
      const f32x4 sq4 = *(const f32x4*)&sqs[cur][ct * 16 + lquad * 4];
      const unsigned colb = (unsigned)(jt + ct * 16 + lquad * 4);
#pragma unroll
      for (int r = 0; r < 4; ++r) {
        net5(p00, p01, p02, p03, p04, packsi(fmaf(-2.0f, acc0[r], sq4[r]), colb + r));
        net5(p10, p11, p12, p13, p14, packsi(fmaf(-2.0f, acc1[r], sq4[r]), colb + r));
      }
    }
    // Single barrier per tile: next commit targets the other buffer.
  }

  // Merge across lquads (lanes sharing lrow hold the same two rows).
#pragma unroll
  for (int m = 16; m < 64; m <<= 1) {
    float o0 = __shfl_xor(p00, m), o1 = __shfl_xor(p01, m), o2 = __shfl_xor(p02, m),
          o3 = __shfl_xor(p03, m), o4 = __shfl_xor(p04, m);
    net5(p00, p01, p02, p03, p04, o0);
    net5(p00, p01, p02, p03, p04, o1);
    net5(p00, p01, p02, p03, p04, o2);
    net5(p00, p01, p02, p03, p04, o3);
    net5(p00, p01, p02, p03, p04, o4);
    o0 = __shfl_xor(p10, m); o1 = __shfl_xor(p11, m); o2 = __shfl_xor(p12, m);
    o3 = __shfl_xor(p13, m); o4 = __shfl_xor(p14, m);
    net5(p10, p11, p12, p13, p14, o0);
    net5(p10, p11, p12, p13, p14, o1);
    net5(p10, p11, p12, p13, p14, o2);
    net5(p10, p11, p12, p13, p14, o3);
    net5(p10, p11, p12, p13, p14, o4);
  }
  if (lquad == 0) {
    const size_t b0i = ((size_t)chunk * NN + myrow0) * 5;
    pscore[b0i + 0] = p00; pscore[b0i + 1] = p01; pscore[b0i + 2] = p02;
    pscore[b0i + 3] = p03; pscore[b0i + 4] = p04;
    const size_t b1i = ((size_t)chunk * NN + myrow1) * 5;
    pscore[b1i + 0] = p10; pscore[b1i + 1] = p11; pscore[b1i + 2] = p12;
    pscore[b1i + 3] = p13; pscore[b1i + 4] = p14;
  }
}

// Kernel 3: chunk merge (packed) -> neg idx -> exact fp32 hinge -> atomic mean.
__global__ __launch_bounds__(256) void final_kernel(const float* __restrict__ x,
                                                    const float* __restrict__ pos,
                                                    const float* __restrict__ pscore,
                                                    float* __restrict__ out) {
  const int wave = threadIdx.x >> 6, lane = threadIdx.x & 63;
  const int row = blockIdx.x * 4 + wave;

  float q0 = PACK_INIT, q1 = PACK_INIT, q2 = PACK_INIT, q3 = PACK_INIT,
        q4 = PACK_INIT;
  if (lane < CH) {
    const float* b = pscore + ((size_t)lane * NN + row) * 5;
    q0 = b[0]; q1 = b[1]; q2 = b[2]; q3 = b[3]; q4 = b[4];
  }
#pragma unroll
  for (int m = 1; m < CH; m <<= 1) {
    float o0 = __shfl_xor(q0, m), o1 = __shfl_xor(q1, m), o2 = __shfl_xor(q2, m),
          o3 = __shfl_xor(q3, m), o4 = __shfl_xor(q4, m);
    net5(q0, q1, q2, q3, q4, o0);
    net5(q0, q1, q2, q3, q4, o1);
    net5(q0, q1, q2, q3, q4, o2);
    net5(q0, q1, q2, q3, q4, o3);
    net5(q0, q1, q2, q3, q4, o4);
  }
  const int nidx = (int)(__float_as_uint(__shfl(q4, 0)) & 0x1FFFu);

  const float2 xv  = ((const float2*)(x   + (size_t)row  * DD))[lane];
  const float2 pv  = ((const float2*)(pos + (size_t)row  * DD))[lane];
  const float2 nvv = ((const float2*)(x   + (size_t)nidx * DD))[lane];
  float a0 = xv.x - pv.x + 1e-6f, a1 = xv.y - pv.y + 1e-6f;
  float b0 = xv.x - nvv.x + 1e-6f, b1 = xv.y - nvv.y + 1e-6f;
  float dap = a0 * a0 + a1 * a1;
  float dan = b0 * b0 + b1 * b1;
#pragma unroll
  for (int off = 32; off; off >>= 1) {
    dap += __shfl_down(dap, off);
    dan += __shfl_down(dan, off);
  }
  __shared__ float hs[4];
  if (lane == 0) hs[wave] = fmaxf(sqrtf(dap) - sqrtf(dan) + 0.3f, 0.0f);
  __syncthreads();
  if (threadIdx.x == 0) {
    float s = hs[0] + hs[1] + hs[2] + hs[3];
    atomicAdd(out, s * (1.0f / 8192.0f));
  }
}

extern "C" void kernel_launch(void* const* d_in, const int* in_sizes, int n_in,
                              void* d_out, int out_size, void* d_ws, size_t ws_size,
                              hipStream_t stream) {
  const float* x   = (const float*)d_in[0];
  const float* pos = (const float*)d_in[1];
  float* out = (float*)d_out;

  char* w = (char*)d_ws;
  unsigned short* xb = (unsigned short*)w;                       // 2 MB
  float* sq = (float*)(w + (size_t)NN * DD * 2);                 // 32 KB
  float* pscore = (float*)(w + (size_t)NN * DD * 2 + (size_t)NN * 4);  // 1.31 MB

  prep_kernel<<<NN / 4, 256, 0, stream>>>(x, xb, sq, out);
  dist_topk_kernel<<<dim3(NN / 128, CH), 256, 0, stream>>>(xb, sq, pscore);
  final_kernel<<<NN / 4, 256, 0, stream>>>(x, pos, pscore, out);
}

// Round 7
// 123.642 us; speedup vs baseline: 3.7671x; 1.0035x over previous
//
#include <hip/hip_runtime.h>

#define NN 8192
#define DD 128
#define CH 16           // column chunks
#define CPC (NN / CH)   // cols per chunk = 512
#define TILES (CPC / 64)

typedef __bf16 bf16x8 __attribute__((ext_vector_type(8)));
typedef float f32x4 __attribute__((ext_vector_type(4)));

#define PACK_INIT __uint_as_float(0x7F7FFFFFu)

// Pack (score, idx): keep high 19 bits of the fp32 score, idx in low 13.
// Monotone bucket-quantization (quantum <= 0.125 for |s|<512); within a
// bucket, smaller idx = smaller float => min-network prefers smaller idx,
// matching reference top_k tie-breaking. Negative scores only occur for
// self (rank-1 by a huge margin), so the inverted idx order there is moot.
static __device__ __forceinline__ float packsi(float s, unsigned idx) {
  return __uint_as_float((__float_as_uint(s) & 0xFFFFE000u) | idx);
}

// Branchless sorted-5 insert (keep 5 smallest): 9 min/max ops, no divergence.
static __device__ __forceinline__ void net5(float& s0, float& s1, float& s2,
                                            float& s3, float& s4, float v) {
  float t1 = fmaxf(s0, v);  s0 = fminf(s0, v);
  float t2 = fmaxf(s1, t1); s1 = fminf(s1, t1);
  float t3 = fmaxf(s2, t2); s2 = fminf(s2, t2);
  float t4 = fmaxf(s3, t3); s3 = fminf(s3, t3);
  s4 = fminf(s4, t4);
}

static __device__ __forceinline__ unsigned short f2bf(float f) {
  unsigned u = __float_as_uint(f);
  u += 0x7FFFu + ((u >> 16) & 1u);   // round-to-nearest-even
  return (unsigned short)(u >> 16);
}

// Kernel 1: f32->bf16 convert, fp32 row sq-norms, zero output scalar.
__global__ __launch_bounds__(256) void prep_kernel(const float* __restrict__ x,
                                                   unsigned short* __restrict__ xb,
                                                   float* __restrict__ sq,
                                                   float* __restrict__ out) {
  const int wave = threadIdx.x >> 6, lane = threadIdx.x & 63;
  const int row = blockIdx.x * 4 + wave;
  const float2 v = ((const float2*)(x + (size_t)row * DD))[lane];
  float ss = v.x * v.x + v.y * v.y;
#pragma unroll
  for (int off = 32; off; off >>= 1) ss += __shfl_down(ss, off);
  if (lane == 0) sq[row] = ss;
  unsigned packed = (unsigned)f2bf(v.x) | ((unsigned)f2bf(v.y) << 16);
  ((unsigned*)(xb + (size_t)row * DD))[lane] = packed;
  if (blockIdx.x == 0 && threadIdx.x == 0) out[0] = 0.0f;
}

// Kernel 2: bf16-MFMA scores + branchless packed top-5.
// R=32 rows/wave (two 16-row groups share each candidate fragment).
// Block = 128 rows x 512 cols; grid (64,16) = 1024 blocks = 4/CU
// (round-6 limiter was occupancy: 512 blocks = 2 waves/SIMD, 15%;
// same per-CU work at 4 waves/SIMD hides ds_read latency + barrier).
__global__ __launch_bounds__(256, 4) void dist_topk_kernel(
    const unsigned short* __restrict__ xb, const float* __restrict__ sq,
    float* __restrict__ pscore) {
  const int t = threadIdx.x;
  const int wave = t >> 6, lane = t & 63;
  const int lrow = lane & 15, lquad = lane >> 4;
  const int rowBase = blockIdx.x * 128;
  const int chunk = blockIdx.y;
  const int j0 = chunk * CPC;

  __shared__ unsigned short colsB[2][64 * DD];   // 2 x 16 KB, XOR-swizzled
  __shared__ float sqs[2][64];

  // My-row fragments (MFMA 2nd operand): lane holds X[row][k=lquad*8+j].
  const int myrow0 = rowBase + wave * 32 + lrow;
  const int myrow1 = myrow0 + 16;
  const unsigned short* ap0 = xb + (size_t)myrow0 * DD + lquad * 8;
  const unsigned short* ap1 = xb + (size_t)myrow1 * DD + lquad * 8;
  bf16x8 a00 = *(const bf16x8*)(ap0);
  bf16x8 a01 = *(const bf16x8*)(ap0 + 32);
  bf16x8 a02 = *(const bf16x8*)(ap0 + 64);
  bf16x8 a03 = *(const bf16x8*)(ap0 + 96);
  bf16x8 a10 = *(const bf16x8*)(ap1);
  bf16x8 a11 = *(const bf16x8*)(ap1 + 32);
  bf16x8 a12 = *(const bf16x8*)(ap1 + 64);
  bf16x8 a13 = *(const bf16x8*)(ap1 + 96);

  // Packed sorted-5 lists, one per row group, named scalars.
  float p00 = PACK_INIT, p01 = PACK_INIT, p02 = PACK_INIT, p03 = PACK_INIT,
        p04 = PACK_INIT;
  float p10 = PACK_INIT, p11 = PACK_INIT, p12 = PACK_INIT, p13 = PACK_INIT,
        p14 = PACK_INIT;

  // Staging closed-form swizzle (round-5 verified).
  const int sr = t >> 4, sch = t & 15;
  const int dst0 = (sr << 4) | (sch ^ (sr & 15));

  const float4* srcv = (const float4*)(xb + (size_t)j0 * DD);
  float4 g0 = srcv[t], g1 = srcv[t + 256], g2 = srcv[t + 512], g3 = srcv[t + 768];
  float sqv = 0.0f;
  if (t < 64) sqv = sq[j0 + t];

  for (int it = 0; it < TILES; ++it) {
    const int jt = j0 + it * 64;
    const int cur = it & 1;
    {
      float4* dstv = (float4*)colsB[cur];
      dstv[dst0] = g0;
      dstv[dst0 + 256] = g1;
      dstv[dst0 + 512] = g2;
      dstv[dst0 + 768] = g3;
      if (t < 64) sqs[cur][t] = sqv;
    }
    if (it + 1 < TILES) {
      const float4* nsrc = (const float4*)(xb + (size_t)(jt + 64) * DD);
      g0 = nsrc[t]; g1 = nsrc[t + 256]; g2 = nsrc[t + 512]; g3 = nsrc[t + 768];
      if (t < 64) sqv = sq[jt + 64 + t];
    }
    __syncthreads();

#pragma unroll
    for (int ct = 0; ct < 4; ++ct) {
      const unsigned short* bb = &colsB[cur][(ct * 16 + lrow) * DD];
      bf16x8 b0 = *(const bf16x8*)(bb + (((0 + lquad) ^ lrow) << 3));
      bf16x8 b1 = *(const bf16x8*)(bb + (((4 + lquad) ^ lrow) << 3));
      bf16x8 b2 = *(const bf16x8*)(bb + (((8 + lquad) ^ lrow) << 3));
      bf16x8 b3 = *(const bf16x8*)(bb + (((12 + lquad) ^ lrow) << 3));
      f32x4 acc0 = {0.f, 0.f, 0.f, 0.f};
      f32x4 acc1 = {0.f, 0.f, 0.f, 0.f};
      acc0 = __builtin_amdgcn_mfma_f32_16x16x32_bf16(b0, a00, acc0, 0, 0, 0);
      acc1 = __builtin_amdgcn_mfma_f32_16x16x32_bf16(b0, a10, acc1, 0, 0, 0);
      acc0 = __builtin_amdgcn_mfma_f32_16x16x32_bf16(b1, a01, acc0, 0, 0, 0);
      acc1 = __builtin_amdgcn_mfma_f32_16x16x32_bf16(b1, a11, acc1, 0, 0, 0);
      acc0 = __builtin_amdgcn_mfma_f32_16x16x32_bf16(b2, a02, acc0, 0, 0, 0);
      acc1 = __builtin_amdgcn_mfma_f32_16x16x32_bf16(b2, a12, acc1, 0, 0, 0);
      acc0 = __builtin_amdgcn_mfma_f32_16x16x32_bf16(b3, a03, acc0, 0, 0, 0);
      acc1 = __builtin_amdgcn_mfma_f32_16x16x32_bf16(b3, a13, acc1, 0, 0, 0);
      // D = Sc^T: reg r -> cand ct*16 + lquad*4 + r; lane -> myrow.
      const f32x4 sq4 = *(const f32x4*)&sqs[cur][ct * 16 + lquad * 4];
      const unsigned colb = (unsigned)(jt + ct * 16 + lquad * 4);
#pragma unroll
      for (int r = 0; r < 4; ++r) {
        net5(p00, p01, p02, p03, p04, packsi(fmaf(-2.0f, acc0[r], sq4[r]), colb + r));
        net5(p10, p11, p12, p13, p14, packsi(fmaf(-2.0f, acc1[r], sq4[r]), colb + r));
      }
    }
    // Single barrier per tile: next commit targets the other buffer.
  }

  // Merge across lquads (lanes sharing lrow hold the same two rows).
#pragma unroll
  for (int m = 16; m < 64; m <<= 1) {
    float o0 = __shfl_xor(p00, m), o1 = __shfl_xor(p01, m), o2 = __shfl_xor(p02, m),
          o3 = __shfl_xor(p03, m), o4 = __shfl_xor(p04, m);
    net5(p00, p01, p02, p03, p04, o0);
    net5(p00, p01, p02, p03, p04, o1);
    net5(p00, p01, p02, p03, p04, o2);
    net5(p00, p01, p02, p03, p04, o3);
    net5(p00, p01, p02, p03, p04, o4);
    o0 = __shfl_xor(p10, m); o1 = __shfl_xor(p11, m); o2 = __shfl_xor(p12, m);
    o3 = __shfl_xor(p13, m); o4 = __shfl_xor(p14, m);
    net5(p10, p11, p12, p13, p14, o0);
    net5(p10, p11, p12, p13, p14, o1);
    net5(p10, p11, p12, p13, p14, o2);
    net5(p10, p11, p12, p13, p14, o3);
    net5(p10, p11, p12, p13, p14, o4);
  }
  if (lquad == 0) {
    const size_t b0i = ((size_t)chunk * NN + myrow0) * 5;
    pscore[b0i + 0] = p00; pscore[b0i + 1] = p01; pscore[b0i + 2] = p02;
    pscore[b0i + 3] = p03; pscore[b0i + 4] = p04;
    const size_t b1i = ((size_t)chunk * NN + myrow1) * 5;
    pscore[b1i + 0] = p10; pscore[b1i + 1] = p11; pscore[b1i + 2] = p12;
    pscore[b1i + 3] = p13; pscore[b1i + 4] = p14;
  }
}

// Kernel 3: chunk merge (packed) -> neg idx -> exact fp32 hinge -> atomic mean.
__global__ __launch_bounds__(256) void final_kernel(const float* __restrict__ x,
                                                    const float* __restrict__ pos,
                                                    const float* __restrict__ pscore,
                                                    float* __restrict__ out) {
  const int wave = threadIdx.x >> 6, lane = threadIdx.x & 63;
  const int row = blockIdx.x * 4 + wave;

  float q0 = PACK_INIT, q1 = PACK_INIT, q2 = PACK_INIT, q3 = PACK_INIT,
        q4 = PACK_INIT;
  if (lane < CH) {
    const float* b = pscore + ((size_t)lane * NN + row) * 5;
    q0 = b[0]; q1 = b[1]; q2 = b[2]; q3 = b[3]; q4 = b[4];
  }
#pragma unroll
  for (int m = 1; m < CH; m <<= 1) {
    float o0 = __shfl_xor(q0, m), o1 = __shfl_xor(q1, m), o2 = __shfl_xor(q2, m),
          o3 = __shfl_xor(q3, m), o4 = __shfl_xor(q4, m);
    net5(q0, q1, q2, q3, q4, o0);
    net5(q0, q1, q2, q3, q4, o1);
    net5(q0, q1, q2, q3, q4, o2);
    net5(q0, q1, q2, q3, q4, o3);
    net5(q0, q1, q2, q3, q4, o4);
  }
  const int nidx = (int)(__float_as_uint(__shfl(q4, 0)) & 0x1FFFu);

  const float2 xv  = ((const float2*)(x   + (size_t)row  * DD))[lane];
  const float2 pv  = ((const float2*)(pos + (size_t)row  * DD))[lane];
  const float2 nvv = ((const float2*)(x   + (size_t)nidx * DD))[lane];
  float a0 = xv.x - pv.x + 1e-6f, a1 = xv.y - pv.y + 1e-6f;
  float b0 = xv.x - nvv.x + 1e-6f, b1 = xv.y - nvv.y + 1e-6f;
  float dap = a0 * a0 + a1 * a1;
  float dan = b0 * b0 + b1 * b1;
#pragma unroll
  for (int off = 32; off; off >>= 1) {
    dap += __shfl_down(dap, off);
    dan += __shfl_down(dan, off);
  }
  __shared__ float hs[4];
  if (lane == 0) hs[wave] = fmaxf(sqrtf(dap) - sqrtf(dan) + 0.3f, 0.0f);
  __syncthreads();
  if (threadIdx.x == 0) {
    float s = hs[0] + hs[1] + hs[2] + hs[3];
    atomicAdd(out, s * (1.0f / 8192.0f));
  }
}

extern "C" void kernel_launch(void* const* d_in, const int* in_sizes, int n_in,
                              void* d_out, int out_size, void* d_ws, size_t ws_size,
                              hipStream_t stream) {
  const float* x   = (const float*)d_in[0];
  const float* pos = (const float*)d_in[1];
  float* out = (float*)d_out;

  char* w = (char*)d_ws;
  unsigned short* xb = (unsigned short*)w;                       // 2 MB
  float* sq = (float*)(w + (size_t)NN * DD * 2);                 // 32 KB
  float* pscore = (float*)(w + (size_t)NN * DD * 2 + (size_t)NN * 4);  // 2.62 MB

  prep_kernel<<<NN / 4, 256, 0, stream>>>(x, xb, sq, out);
  dist_topk_kernel<<<dim3(NN / 128, CH), 256, 0, stream>>>(xb, sq, pscore);
  final_kernel<<<NN / 4, 256, 0, stream>>>(x, pos, pscore, out);
}